// Round 5
// baseline (701.000 us; speedup 1.0000x reference)
//
#include <hip/hip_runtime.h>

#define NEG_SLOPE 0.2f
static constexpr float BN_INV = 0.9999950000374997f; // 1/sqrt(1+1e-5)

typedef __bf16 bf16x8 __attribute__((ext_vector_type(8)));
typedef float  f32x4  __attribute__((ext_vector_type(4)));

__device__ inline float4 bf4f(ushort4 u){
  float4 r;
  r.x = __uint_as_float((unsigned)u.x << 16);
  r.y = __uint_as_float((unsigned)u.y << 16);
  r.z = __uint_as_float((unsigned)u.z << 16);
  r.w = __uint_as_float((unsigned)u.w << 16);
  return r;
}
__device__ inline ushort4 f4bf(float4 v){
  ushort4 u;
  u.x = __builtin_bit_cast(unsigned short, (__bf16)v.x);
  u.y = __builtin_bit_cast(unsigned short, (__bf16)v.y);
  u.z = __builtin_bit_cast(unsigned short, (__bf16)v.z);
  u.w = __builtin_bit_cast(unsigned short, (__bf16)v.w);
  return u;
}

// ===================== CSR build =====================
__global__ void hist_kernel(const int* __restrict__ dst, int* __restrict__ cnt, int E){
  int e = blockIdx.x*256 + threadIdx.x;
  if (e < E) atomicAdd(&cnt[dst[e]], 1);
}

// multiblock scan: part 1 — per-1024-block local scan + block totals
__global__ __launch_bounds__(1024) void scan1_kernel(int* __restrict__ cnt_cursor,
                                                     int* __restrict__ offs,
                                                     int* __restrict__ bsum, int n){
  __shared__ int wsum[16];
  int tid = threadIdx.x, lane = tid & 63, wv = tid >> 6;
  int i = blockIdx.x*1024 + tid;
  int v = (i < n) ? cnt_cursor[i] : 0;
  int x = v;
#pragma unroll
  for (int off = 1; off < 64; off <<= 1){
    int t = __shfl_up(x, off);
    if (lane >= off) x += t;
  }
  if (lane == 63) wsum[wv] = x;
  __syncthreads();
  int y = (lane < 16) ? wsum[lane] : 0;
#pragma unroll
  for (int off = 1; off < 16; off <<= 1){
    int t = __shfl_up(y, off);
    if (lane >= off) y += t;
  }
  int excl  = (wv == 0) ? 0 : __shfl(y, wv - 1);
  int total = __shfl(y, 15);
  int inc = excl + x;                       // block-local inclusive
  if (i < n){ offs[i+1] = inc; cnt_cursor[i] = inc - v; }
  if (tid == 0) bsum[blockIdx.x] = total;
}

// part 2+3 merged — each block shuffle-reduces bsum[0..bid) itself (nb <= 64)
__global__ __launch_bounds__(1024) void scan3_kernel(int* __restrict__ offs, int* __restrict__ cursor,
                                                     const int* __restrict__ bsum, int n){
  __shared__ int base_s;
  if (threadIdx.x < 64){
    int lane = threadIdx.x;
    int v = (lane < (int)blockIdx.x) ? bsum[lane] : 0;
#pragma unroll
    for (int off = 1; off < 64; off <<= 1) v += __shfl_xor(v, off);
    if (lane == 0) base_s = v;
  }
  __syncthreads();
  int base = base_s;
  int i = blockIdx.x*1024 + threadIdx.x;
  if (i < n){ offs[i+1] += base; cursor[i] += base; }
  if (i == 0) offs[0] = 0;
}

// scatter: permute src + edge_attr into CSR(dst) order
__global__ void scatter_kernel(const int* __restrict__ src, const int* __restrict__ dst,
                               const float* __restrict__ ea, int* __restrict__ cursor,
                               int* __restrict__ perm_src, float* __restrict__ ea_perm, int E){
  int e = blockIdx.x*256 + threadIdx.x;
  if (e >= E) return;
  int d = dst[e];
  int pos = atomicAdd(&cursor[d], 1);
  perm_src[pos] = src[e];
#pragma unroll
  for (int k = 0; k < 6; ++k) ea_perm[(size_t)pos*6 + k] = ea[(size_t)e*6 + k];
}

// ===================== generic fp32 GEMM (MLP path), strided C =====================
template<bool USE_BIAS, bool USE_BN, bool USE_RELU, typename OutT>
__global__ __launch_bounds__(256) void gemm_kernel(
    const float* __restrict__ A, const float* __restrict__ W,
    const float* __restrict__ bias, const float* __restrict__ gam, const float* __restrict__ bet,
    OutT* __restrict__ C, int M, int N, int K, int LDC)
{
  __shared__ float As[32][68];
  __shared__ float Bs[32][64];
  int tid = threadIdx.x;
  int tx = tid & 15, ty = tid >> 4;
  int bn0 = blockIdx.x * 64, bm0 = blockIdx.y * 64;
  float acc[4][4] = {};
  for (int k0 = 0; k0 < K; k0 += 32){
    int kk = tid & 31, mm0 = tid >> 5;
#pragma unroll
    for (int r = 0; r < 8; ++r){
      int ml = mm0 + r*8;
      int m = bm0 + ml;
      As[kk][ml] = (m < M) ? A[(size_t)m*K + k0 + kk] : 0.f;
    }
    int nn = tid & 63, kb = tid >> 6;
#pragma unroll
    for (int r = 0; r < 8; ++r){
      int kl = kb + r*4;
      int n = bn0 + nn;
      Bs[kl][nn] = (n < N) ? W[(size_t)(k0 + kl)*N + n] : 0.f;
    }
    __syncthreads();
#pragma unroll
    for (int k = 0; k < 32; ++k){
      float4 a4 = *reinterpret_cast<const float4*>(&As[k][ty*4]);
      float4 b4 = *reinterpret_cast<const float4*>(&Bs[k][tx*4]);
      acc[0][0] += a4.x*b4.x; acc[0][1] += a4.x*b4.y; acc[0][2] += a4.x*b4.z; acc[0][3] += a4.x*b4.w;
      acc[1][0] += a4.y*b4.x; acc[1][1] += a4.y*b4.y; acc[1][2] += a4.y*b4.z; acc[1][3] += a4.y*b4.w;
      acc[2][0] += a4.z*b4.x; acc[2][1] += a4.z*b4.y; acc[2][2] += a4.z*b4.z; acc[2][3] += a4.z*b4.w;
      acc[3][0] += a4.w*b4.x; acc[3][1] += a4.w*b4.y; acc[3][2] += a4.w*b4.z; acc[3][3] += a4.w*b4.w;
    }
    __syncthreads();
  }
#pragma unroll
  for (int i = 0; i < 4; ++i){
    int m = bm0 + ty*4 + i;
    if (m < M){
#pragma unroll
      for (int j = 0; j < 4; ++j){
        int n = bn0 + tx*4 + j;
        if (n < N){
          float c = acc[i][j];
          if (USE_BIAS) c += bias[n];
          if (USE_BN)   c = gam[n]*c*BN_INV + bet[n];
          if (USE_RELU) c = fmaxf(c, 0.f);
          C[(size_t)m*LDC + n] = (OutT)c;
        }
      }
    }
  }
}

// wtrans for the 3 GAT weight matrices + folded We@ae (z==3 slice)
__global__ void wtrans3_kernel(const float* __restrict__ W0, const float* __restrict__ W1,
                               const float* __restrict__ W2, __bf16* __restrict__ Wt,
                               const float* __restrict__ We1, const float* __restrict__ ae1,
                               const float* __restrict__ We2, const float* __restrict__ ae2,
                               const float* __restrict__ We3, const float* __restrict__ ae3,
                               float* __restrict__ M){
  if (blockIdx.z == 3){
    if (blockIdx.x != 0 || blockIdx.y != 0) return;
    int t = threadIdx.x;   // 256, use first 102
    if (t < 96){
      const float* We = (t < 48) ? We1 : We2;
      const float* ae = (t < 48) ? ae1 : ae2;
      int u = t % 48, k = u / 8, h = u % 8;
      float s = 0.f;
      for (int c = 0; c < 32; ++c) s += We[k*256 + h*32 + c] * ae[h*32 + c];
      M[t] = s;
    } else if (t < 102){
      int k = t - 96;
      float s = 0.f;
      for (int c = 0; c < 256; ++c) s += We3[k*256 + c] * ae3[c];
      M[t] = s;
    }
    return;
  }
  __shared__ float tile[32][33];
  const float* W = (blockIdx.z == 0) ? W0 : (blockIdx.z == 1) ? W1 : W2;
  __bf16* D = Wt + (size_t)blockIdx.z * 65536;
  int n0 = blockIdx.x*32, k0 = blockIdx.y*32;
  int t = threadIdx.x;
  int nl = t & 31, kl = t >> 5;
#pragma unroll
  for (int r = 0; r < 4; ++r)
    tile[kl + r*8][nl] = W[(size_t)(k0 + kl + r*8)*256 + n0 + nl];
  __syncthreads();
  int nl2 = t >> 3, kc = (t & 7)*4;
#pragma unroll
  for (int j = 0; j < 4; ++j)
    D[(size_t)(n0 + nl2)*256 + k0 + kc + j] = (__bf16)tile[kc + j][nl2];
}

// ===================== bf16 MFMA GEMM: C[M,N] = A[M,K] * Bt[N,K]^T =====================
// BM=128, BN=128, BK=64; 256 thr = 4 waves (2x2), each wave 64x64 via 4x4 mfma_16x16x32
// AF32: A is f32, converted to bf16 during staging (bounds-checked).
// ALSD==8: fuse per-row attention dots als/ald (H=8) from f32 accumulators, direct store.
// ALSD==1: fuse per-row dots (H=1, full 256-col row) via atomicAdd into zeroed als/ald.
template<bool AF32, int ALSD, typename OutT>
__global__ __launch_bounds__(256) void mfma_gemm_kernel(
    const void* __restrict__ Aptr, const __bf16* __restrict__ Bt,
    OutT* __restrict__ C, int M, int N, int K,
    const float* __restrict__ a_s, const float* __restrict__ a_d,
    float* __restrict__ als, float* __restrict__ ald)
{
  const __bf16* Ab = (const __bf16*)Aptr;
  const float*  Af = (const float*) Aptr;
  __shared__ __bf16 As[128*72];
  __shared__ __bf16 Bs[128*72];
  int tid = threadIdx.x;
  int lane = tid & 63, w = tid >> 6;
  int quad = lane >> 4, l16 = lane & 15;
  int wm = (w & 1) * 64, wn = (w >> 1) * 64;
  int bn0 = blockIdx.x * 128, bm0 = blockIdx.y * 128;
  f32x4 acc[4][4] = {};
  for (int k0 = 0; k0 < K; k0 += 64){
#pragma unroll
    for (int p = 0; p < 4; ++p){
      int idx = p*256 + tid;
      int row = idx >> 3, ch = idx & 7;
      uint4 av;
      if constexpr (AF32){
        av = make_uint4(0,0,0,0);
        int m = bm0 + row;
        if (m < M){
          const float4* A4 = reinterpret_cast<const float4*>(&Af[(size_t)m*K + k0 + ch*8]);
          float4 x0 = A4[0], x1 = A4[1];
          ushort4 u0 = f4bf(x0), u1 = f4bf(x1);
          av = make_uint4((unsigned)u0.x | ((unsigned)u0.y << 16),
                          (unsigned)u0.z | ((unsigned)u0.w << 16),
                          (unsigned)u1.x | ((unsigned)u1.y << 16),
                          (unsigned)u1.z | ((unsigned)u1.w << 16));
        }
      } else {
        av = *reinterpret_cast<const uint4*>(&Ab[(size_t)(bm0 + row)*K + k0 + ch*8]);
      }
      *reinterpret_cast<uint4*>(&As[row*72 + ch*8]) = av;
      int n = bn0 + row;
      uint4 bv = make_uint4(0,0,0,0);
      if (n < N) bv = *reinterpret_cast<const uint4*>(&Bt[(size_t)n*K + k0 + ch*8]);
      *reinterpret_cast<uint4*>(&Bs[row*72 + ch*8]) = bv;
    }
    __syncthreads();
#pragma unroll
    for (int s = 0; s < 2; ++s){
      bf16x8 af[4], bfr[4];
#pragma unroll
      for (int t4 = 0; t4 < 4; ++t4){
        af[t4]  = *reinterpret_cast<const bf16x8*>(&As[(wm + t4*16 + l16)*72 + s*32 + quad*8]);
        bfr[t4] = *reinterpret_cast<const bf16x8*>(&Bs[(wn + t4*16 + l16)*72 + s*32 + quad*8]);
      }
#pragma unroll
      for (int mt = 0; mt < 4; ++mt)
#pragma unroll
        for (int nt = 0; nt < 4; ++nt)
          acc[mt][nt] = __builtin_amdgcn_mfma_f32_16x16x32_bf16(af[mt], bfr[nt], acc[mt][nt], 0, 0, 0);
    }
    __syncthreads();
  }
  // C/D layout: col = lane&15, row = quad*4 + reg  [m89-verified]
#pragma unroll
  for (int mt = 0; mt < 4; ++mt){
#pragma unroll
    for (int nt = 0; nt < 4; ++nt){
      int n = bn0 + wn + nt*16 + l16;
      if (n < N){
#pragma unroll
        for (int r = 0; r < 4; ++r){
          int m = bm0 + wm + mt*16 + quad*4 + r;
          if (m < M) C[(size_t)m*N + n] = (OutT)(acc[mt][nt][r]);
        }
      }
    }
  }
  if constexpr (ALSD != 0){
    float av4[4], dv4[4];
#pragma unroll
    for (int nt = 0; nt < 4; ++nt){
      int n = bn0 + wn + nt*16 + l16;   // N==256 for xp GEMMs, always in range
      av4[nt] = a_s[n];
      dv4[nt] = a_d[n];
    }
    int hb = (bn0 + wn) >> 5;           // first head in this wave's 64-col span (ALSD==8)
#pragma unroll
    for (int mt = 0; mt < 4; ++mt){
#pragma unroll
      for (int r = 0; r < 4; ++r){
        float s0 = acc[mt][0][r]*av4[0] + acc[mt][1][r]*av4[1];
        float s1 = acc[mt][2][r]*av4[2] + acc[mt][3][r]*av4[3];
        float d0 = acc[mt][0][r]*dv4[0] + acc[mt][1][r]*dv4[1];
        float d1 = acc[mt][2][r]*dv4[2] + acc[mt][3][r]*dv4[3];
#pragma unroll
        for (int off = 1; off < 16; off <<= 1){
          s0 += __shfl_xor(s0, off); s1 += __shfl_xor(s1, off);
          d0 += __shfl_xor(d0, off); d1 += __shfl_xor(d1, off);
        }
        if (l16 == 0){
          int m = bm0 + wm + mt*16 + quad*4 + r;
          if (m < M){
            if constexpr (ALSD == 8){
              als[m*8 + hb]     = s0; als[m*8 + hb + 1] = s1;
              ald[m*8 + hb]     = d0; ald[m*8 + hb + 1] = d1;
            } else {  // ALSD == 1: partial over this wave's 64 cols -> atomic
              atomicAdd(&als[m], s0 + s1);
              atomicAdd(&ald[m], d0 + d1);
            }
          }
        }
      }
    }
  }
}

// ===================== classify GEMM: BM=256, BN=128, 512 thr = 8 waves (4m x 2n) ========
// C f32 = A[M,K]bf16 * W[K,N]f32 + bias.  W converted to bf16 + transposed in staging
// (kills the separate wtrans pass).  M must be a multiple of 256.
// XCD-chunk swizzle: all 8 m-blocks of one B-panel land on one XCD -> B read from L3 ~once.
__global__ __launch_bounds__(512) void mfma_cls_kernel(
    const __bf16* __restrict__ A, const float* __restrict__ W,
    const float* __restrict__ bias, float* __restrict__ C, int M, int N, int K)
{
  __shared__ __bf16 As[256*72];
  __shared__ __bf16 Bs[128*72];
  int tid = threadIdx.x;
  int lane = tid & 63, w = tid >> 6;       // 8 waves
  int quad = lane >> 4, l16 = lane & 15;
  int wm = (w >> 1) * 64, wn = (w & 1) * 64;
  int nwg = gridDim.x;                     // 8 * NB
  int chunk = nwg >> 3;
  int orig = (blockIdx.x & 7) * chunk + (blockIdx.x >> 3);
  int bm0 = (orig & 7) * 256, bn0 = (orig >> 3) * 128;
  int kr = tid >> 5;                       // 0..15 (k-row within pass)
  int nq = (tid & 31) * 4;                 // n-quad offset 0..124
  bool nok = (bn0 + nq) < N;               // float4 aligned; N % 4 == 0
  f32x4 acc[4][4] = {};
  for (int k0 = 0; k0 < K; k0 += 64){
#pragma unroll
    for (int p = 0; p < 4; ++p){
      int idx = p*512 + tid;
      int row = idx >> 3, ch = idx & 7;    // row 0..255
      uint4 av = *reinterpret_cast<const uint4*>(&A[(size_t)(bm0 + row)*K + k0 + ch*8]);
      *reinterpret_cast<uint4*>(&As[row*72 + ch*8]) = av;
    }
#pragma unroll
    for (int p = 0; p < 4; ++p){
      int kl = p*16 + kr;                  // 0..63
      float4 bv = make_float4(0.f,0.f,0.f,0.f);
      if (nok) bv = *reinterpret_cast<const float4*>(&W[(size_t)(k0 + kl)*N + bn0 + nq]);
      Bs[(nq+0)*72 + kl] = (__bf16)bv.x;
      Bs[(nq+1)*72 + kl] = (__bf16)bv.y;
      Bs[(nq+2)*72 + kl] = (__bf16)bv.z;
      Bs[(nq+3)*72 + kl] = (__bf16)bv.w;
    }
    __syncthreads();
#pragma unroll
    for (int s = 0; s < 2; ++s){
      bf16x8 af[4], bfr[4];
#pragma unroll
      for (int t4 = 0; t4 < 4; ++t4){
        af[t4]  = *reinterpret_cast<const bf16x8*>(&As[(wm + t4*16 + l16)*72 + s*32 + quad*8]);
        bfr[t4] = *reinterpret_cast<const bf16x8*>(&Bs[(wn + t4*16 + l16)*72 + s*32 + quad*8]);
      }
#pragma unroll
      for (int mt = 0; mt < 4; ++mt)
#pragma unroll
        for (int nt = 0; nt < 4; ++nt)
          acc[mt][nt] = __builtin_amdgcn_mfma_f32_16x16x32_bf16(af[mt], bfr[nt], acc[mt][nt], 0, 0, 0);
    }
    __syncthreads();
  }
#pragma unroll
  for (int mt = 0; mt < 4; ++mt){
#pragma unroll
    for (int nt = 0; nt < 4; ++nt){
      int n = bn0 + wn + nt*16 + l16;
      if (n < N){
        float bv = bias[n];
#pragma unroll
        for (int r = 0; r < 4; ++r){
          int m = bm0 + wm + mt*16 + quad*4 + r;   // M % 256 == 0: always in range
          C[(size_t)m*N + n] = acc[mt][nt][r] + bv;
        }
      }
    }
  }
}

// ===================== fused per-node attention + aggregation (single pass, H=8) ==========
// w_i = exp(alpha_i)/(sum exp + 1e-16); max-subtraction omitted (|alpha| small)
__global__ void agg8_kernel(const int* __restrict__ offs, const int* __restrict__ perm_src,
                            const float* __restrict__ ea_perm, const float* __restrict__ Mf,
                            const float* __restrict__ als, const float* __restrict__ ald,
                            const __bf16* __restrict__ xp, const float* __restrict__ bias,
                            __bf16* __restrict__ out, int Nn){
  int gid = blockIdx.x*blockDim.x + threadIdx.x;
  int wave = gid >> 6, lane = threadIdx.x & 63;
  if (wave >= Nn) return;
  int beg = offs[wave], end = offs[wave+1];
  int hsel = lane >> 3;

  float mk[6];
#pragma unroll
  for (int k = 0; k < 6; ++k) mk[k] = Mf[k*8 + hsel];
  float aldv = ald[(size_t)wave*8 + hsel];

  const ushort4* X4 = reinterpret_cast<const ushort4*>(xp);
  float4 acc = make_float4(0.f,0.f,0.f,0.f);
  float den = 0.f;

  int i = beg;
  // 8-deep unroll: more xp gathers in flight per wave
  for (; i + 7 < end; i += 8){
    int ss[8];
#pragma unroll
    for (int u = 0; u < 8; ++u) ss[u] = perm_src[i+u];
    float ee[8];
#pragma unroll
    for (int u = 0; u < 8; ++u){
      float a = als[(size_t)ss[u]*8 + hsel] + aldv;
#pragma unroll
      for (int k = 0; k < 6; ++k) a += ea_perm[(size_t)(i+u)*6 + k] * mk[k];
      a = (a > 0.f) ? a : NEG_SLOPE*a;
      ee[u] = __expf(a);
      den += ee[u];
    }
#pragma unroll
    for (int u = 0; u < 8; ++u){
      float4 xv = bf4f(X4[(size_t)ss[u]*64 + lane]);
      acc.x += xv.x*ee[u]; acc.y += xv.y*ee[u];
      acc.z += xv.z*ee[u]; acc.w += xv.w*ee[u];
    }
  }
  for (; i + 3 < end; i += 4){
    int s0 = perm_src[i], s1 = perm_src[i+1], s2 = perm_src[i+2], s3 = perm_src[i+3];
    float a0 = als[(size_t)s0*8 + hsel] + aldv;
    float a1 = als[(size_t)s1*8 + hsel] + aldv;
    float a2 = als[(size_t)s2*8 + hsel] + aldv;
    float a3 = als[(size_t)s3*8 + hsel] + aldv;
#pragma unroll
    for (int k = 0; k < 6; ++k){
      a0 += ea_perm[(size_t)i*6 + k]     * mk[k];
      a1 += ea_perm[(size_t)(i+1)*6 + k] * mk[k];
      a2 += ea_perm[(size_t)(i+2)*6 + k] * mk[k];
      a3 += ea_perm[(size_t)(i+3)*6 + k] * mk[k];
    }
    a0 = (a0 > 0.f) ? a0 : NEG_SLOPE*a0;
    a1 = (a1 > 0.f) ? a1 : NEG_SLOPE*a1;
    a2 = (a2 > 0.f) ? a2 : NEG_SLOPE*a2;
    a3 = (a3 > 0.f) ? a3 : NEG_SLOPE*a3;
    float e0 = __expf(a0), e1 = __expf(a1), e2 = __expf(a2), e3 = __expf(a3);
    den += (e0 + e1) + (e2 + e3);
    float4 x0 = bf4f(X4[(size_t)s0*64 + lane]);
    float4 x1 = bf4f(X4[(size_t)s1*64 + lane]);
    float4 x2 = bf4f(X4[(size_t)s2*64 + lane]);
    float4 x3 = bf4f(X4[(size_t)s3*64 + lane]);
    acc.x += x0.x*e0 + x1.x*e1 + x2.x*e2 + x3.x*e3;
    acc.y += x0.y*e0 + x1.y*e1 + x2.y*e2 + x3.y*e3;
    acc.z += x0.z*e0 + x1.z*e1 + x2.z*e2 + x3.z*e3;
    acc.w += x0.w*e0 + x1.w*e1 + x2.w*e2 + x3.w*e3;
  }
  for (; i < end; ++i){
    int s = perm_src[i];
    float a = als[(size_t)s*8 + hsel] + aldv;
#pragma unroll
    for (int k = 0; k < 6; ++k) a += ea_perm[(size_t)i*6 + k] * mk[k];
    a = (a > 0.f) ? a : NEG_SLOPE*a;
    float e = __expf(a);
    den += e;
    float4 xv = bf4f(X4[(size_t)s*64 + lane]);
    acc.x += xv.x*e; acc.y += xv.y*e; acc.z += xv.z*e; acc.w += xv.w*e;
  }

  float r = 1.f / (den + 1e-16f);
  float4 bv = reinterpret_cast<const float4*>(bias)[lane];
  acc.x = fmaxf(acc.x*r + bv.x, 0.f); acc.y = fmaxf(acc.y*r + bv.y, 0.f);
  acc.z = fmaxf(acc.z*r + bv.z, 0.f); acc.w = fmaxf(acc.w*r + bv.w, 0.f);
  reinterpret_cast<ushort4*>(out)[(size_t)wave*64 + lane] = f4bf(acc);
}

// ===================== layer-3 aggregation, QUERIED NODES ONLY (H=1) ==========
// One wave per batch element b; node = ids[b]; writes f32 directly into comb[b][0:256].
__global__ void agg1q_kernel(const int* __restrict__ ids, const int* __restrict__ offs,
                             const int* __restrict__ perm_src, const float* __restrict__ ea_perm,
                             const float* __restrict__ Mf, const float* __restrict__ als,
                             const float* __restrict__ ald, const __bf16* __restrict__ xp,
                             const float* __restrict__ bias, float* __restrict__ comb, int B){
  int gid = blockIdx.x*blockDim.x + threadIdx.x;
  int wave = gid >> 6, lane = threadIdx.x & 63;
  if (wave >= B) return;
  int node = ids[wave];
  int beg = offs[node], end = offs[node+1];

  float mk[6];
#pragma unroll
  for (int k = 0; k < 6; ++k) mk[k] = Mf[k];
  float aldv = ald[node];

  const ushort4* X4 = reinterpret_cast<const ushort4*>(xp);
  float4 acc = make_float4(0.f,0.f,0.f,0.f);
  float den = 0.f;

  int i = beg;
  for (; i + 3 < end; i += 4){
    int s0 = perm_src[i], s1 = perm_src[i+1], s2 = perm_src[i+2], s3 = perm_src[i+3];
    float a0 = als[s0] + aldv, a1 = als[s1] + aldv;
    float a2 = als[s2] + aldv, a3 = als[s3] + aldv;
#pragma unroll
    for (int k = 0; k < 6; ++k){
      a0 += ea_perm[(size_t)i*6 + k]     * mk[k];
      a1 += ea_perm[(size_t)(i+1)*6 + k] * mk[k];
      a2 += ea_perm[(size_t)(i+2)*6 + k] * mk[k];
      a3 += ea_perm[(size_t)(i+3)*6 + k] * mk[k];
    }
    a0 = (a0 > 0.f) ? a0 : NEG_SLOPE*a0;
    a1 = (a1 > 0.f) ? a1 : NEG_SLOPE*a1;
    a2 = (a2 > 0.f) ? a2 : NEG_SLOPE*a2;
    a3 = (a3 > 0.f) ? a3 : NEG_SLOPE*a3;
    float e0 = __expf(a0), e1 = __expf(a1), e2 = __expf(a2), e3 = __expf(a3);
    den += (e0 + e1) + (e2 + e3);
    float4 x0 = bf4f(X4[(size_t)s0*64 + lane]);
    float4 x1 = bf4f(X4[(size_t)s1*64 + lane]);
    float4 x2 = bf4f(X4[(size_t)s2*64 + lane]);
    float4 x3 = bf4f(X4[(size_t)s3*64 + lane]);
    acc.x += x0.x*e0 + x1.x*e1 + x2.x*e2 + x3.x*e3;
    acc.y += x0.y*e0 + x1.y*e1 + x2.y*e2 + x3.y*e3;
    acc.z += x0.z*e0 + x1.z*e1 + x2.z*e2 + x3.z*e3;
    acc.w += x0.w*e0 + x1.w*e1 + x2.w*e2 + x3.w*e3;
  }
  for (; i < end; ++i){
    int s = perm_src[i];
    float a = als[s] + aldv;
#pragma unroll
    for (int k = 0; k < 6; ++k) a += ea_perm[(size_t)i*6 + k] * mk[k];
    a = (a > 0.f) ? a : NEG_SLOPE*a;
    float e = __expf(a);
    den += e;
    float4 xv = bf4f(X4[(size_t)s*64 + lane]);
    acc.x += xv.x*e; acc.y += xv.y*e; acc.z += xv.z*e; acc.w += xv.w*e;
  }

  float r = 1.f / (den + 1e-16f);
  float4 bv = reinterpret_cast<const float4*>(bias)[lane];
  acc.x = acc.x*r + bv.x; acc.y = acc.y*r + bv.y;
  acc.z = acc.z*r + bv.z; acc.w = acc.w*r + bv.w;
  reinterpret_cast<float4*>(comb)[(size_t)wave*128 + lane] = acc;  // cols [0,256)
}

// ===================== MLP path =====================
__global__ void h1_kernel(const float* __restrict__ nf, const float* __restrict__ w1,
                          const float* __restrict__ b1, const float* __restrict__ g,
                          const float* __restrict__ be, float* __restrict__ out){
  int b = blockIdx.x, j = threadIdx.x;
  float s = b1[j];
#pragma unroll
  for (int k = 0; k < 10; ++k) s += nf[b*10 + k] * w1[k*256 + j];
  s = g[j]*s*BN_INV + be[j];
  out[b*256 + j] = fmaxf(s, 0.f);
}

// ===================== host =====================
extern "C" void kernel_launch(void* const* d_in, const int* in_sizes, int n_in,
                              void* d_out, int out_size, void* d_ws, size_t ws_size,
                              hipStream_t stream)
{
  const int*   ids   = (const int*)  d_in[0];
  const float* nf    = (const float*)d_in[1];
  const int*   eidx  = (const int*)  d_in[2];
  const float* eattr = (const float*)d_in[3];
  const float* emb   = (const float*)d_in[4];
  const float* w1    = (const float*)d_in[5];
  const float* b1    = (const float*)d_in[6];
  const float* g1    = (const float*)d_in[7];
  const float* be1   = (const float*)d_in[8];
  const float* w2    = (const float*)d_in[9];
  const float* b2    = (const float*)d_in[10];
  const float* g2    = (const float*)d_in[11];
  const float* be2   = (const float*)d_in[12];
  const float* gW[3]  = {(const float*)d_in[13], (const float*)d_in[19], (const float*)d_in[25]};
  const float* gas[3] = {(const float*)d_in[14], (const float*)d_in[20], (const float*)d_in[26]};
  const float* gad[3] = {(const float*)d_in[15], (const float*)d_in[21], (const float*)d_in[27]};
  const float* gWe[3] = {(const float*)d_in[16], (const float*)d_in[22], (const float*)d_in[28]};
  const float* gae[3] = {(const float*)d_in[17], (const float*)d_in[23], (const float*)d_in[29]};
  const float* gb[3]  = {(const float*)d_in[18], (const float*)d_in[24], (const float*)d_in[30]};
  const float* fus_w  = (const float*)d_in[31];
  const float* fus_b  = (const float*)d_in[32];
  const float* fus_g  = (const float*)d_in[33];
  const float* fus_be = (const float*)d_in[34];
  const float* cls_w  = (const float*)d_in[35];
  const float* cls_b  = (const float*)d_in[36];

  const int E  = in_sizes[3] / 6;     // 320000
  const int Nn = in_sizes[4] / 256;   // 20000
  const int B  = in_sizes[0];         // 2048
  const int Ncls = in_sizes[36];      // 20000
  const int Npad = (Nn + 127) & ~127; // 20096
  const int* src = eidx;
  const int* dst = eidx + E;

  char* wbase = (char*)d_ws;
  size_t woff = 0;
  auto carve = [&](size_t bytes)->void*{
    void* p = wbase + woff;
    woff = (woff + bytes + 255) & ~(size_t)255;
    return p;
  };
  int*    offs     = (int*)   carve((size_t)(Nn+1)*4);
  // zero-region: cursor, als3, ald3 carved contiguously, cleared by ONE memset
  int*    cursor   = (int*)   carve((size_t)Nn*4);
  float*  als3     = (float*) carve((size_t)Nn*4);
  float*  ald3     = (float*) carve((size_t)Nn*4);
  size_t  zero_bytes = (size_t)((char*)ald3 - (char*)cursor) + (size_t)Nn*4;
  int*    bsum     = (int*)   carve(64*4);
  int*    perm_src = (int*)   carve((size_t)E*4);
  float*  ea_perm  = (float*) carve((size_t)E*6*4);
  __bf16* xb0      = (__bf16*)carve((size_t)Npad*256*2);
  __bf16* xb1      = (__bf16*)carve((size_t)Npad*256*2);
  __bf16* xpb      = (__bf16*)carve((size_t)Npad*256*2);
  __bf16* gWt      = (__bf16*)carve((size_t)3*256*256*2);
  float*  als      = (float*) carve((size_t)Nn*8*4);
  float*  ald      = (float*) carve((size_t)Nn*8*4);
  float*  Mfold    = (float*) carve(128*4);
  float*  h1b      = (float*) carve((size_t)B*256*4);
  float*  comb     = (float*) carve((size_t)B*512*4);
  __bf16* fusedb   = (__bf16*)carve((size_t)B*256*2);
  (void)ws_size; (void)n_in; (void)out_size;

  const int nb1024 = (Nn + 1023) / 1024;   // 20 scan blocks (<= 64)

  // ---- CSR build (dst fixed across layers) + zero als3/ald3 for layer-3 atomics ----
  hipMemsetAsync(cursor, 0, zero_bytes, stream);
  hist_kernel<<<(E+255)/256, 256, 0, stream>>>(dst, cursor, E);
  scan1_kernel<<<nb1024, 1024, 0, stream>>>(cursor, offs, bsum, Nn);
  scan3_kernel<<<nb1024, 1024, 0, stream>>>(offs, cursor, bsum, Nn);
  scatter_kernel<<<(E+255)/256, 256, 0, stream>>>(src, dst, eattr, cursor,
                                                  perm_src, ea_perm, E);

  // ---- weight prep (wtrans3 z=3 slice computes Mfold; cls_w read directly by cls) ----
  wtrans3_kernel<<<dim3(8, 8, 4), 256, 0, stream>>>(gW[0], gW[1], gW[2], gWt,
                                                    gWe[0], gae[0], gWe[1], gae[1],
                                                    gWe[2], gae[2], Mfold);

  // ---- GAT layers ----
  dim3 mfma_grid_xp(2, Npad/128);
  int node_blocks = (Nn*64 + 255)/256;

  // layer 1: A = emb (f32, converted in staging), fused alsd (H=8)
  mfma_gemm_kernel<true, 8, __bf16><<<mfma_grid_xp, 256, 0, stream>>>(
      emb, gWt, xpb, Nn, 256, 256, gas[0], gad[0], als, ald);
  agg8_kernel<<<node_blocks, 256, 0, stream>>>(offs, perm_src, ea_perm, Mfold,
                                               als, ald, xpb, gb[0], xb1, Nn);
  // layer 2
  mfma_gemm_kernel<false, 8, __bf16><<<mfma_grid_xp, 256, 0, stream>>>(
      xb1, gWt + 65536, xpb, Nn, 256, 256, gas[1], gad[1], als, ald);
  agg8_kernel<<<node_blocks, 256, 0, stream>>>(offs, perm_src, ea_perm, Mfold + 48,
                                               als, ald, xpb, gb[1], xb0, Nn);
  // layer 3 (H=1): alsd fused via atomics into zeroed als3/ald3; aggregate ONLY
  // the queried nodes, writing f32 straight into comb[:, 0:256]
  mfma_gemm_kernel<false, 1, __bf16><<<mfma_grid_xp, 256, 0, stream>>>(
      xb0, gWt + 131072, xpb, Nn, 256, 256, gas[2], gad[2], als3, ald3);
  agg1q_kernel<<<(B*64 + 255)/256, 256, 0, stream>>>(ids, offs, perm_src, ea_perm,
                                                     Mfold + 96, als3, ald3, xpb, gb[2], comb, B);

  // ---- MLP path: netemb written directly into comb[:, 256:512] ----
  h1_kernel<<<B, 256, 0, stream>>>(nf, w1, b1, g1, be1, h1b);
  gemm_kernel<true,true,true,float><<<dim3(4, B/64), 256, 0, stream>>>(
      h1b, w2, b2, g2, be2, comb + 256, B, 256, 256, 512);

  // ---- fuse (bf16 out) + classify (BM=256 MFMA, XCD-swizzled, direct f32 W read) ----
  gemm_kernel<true,true,true,__bf16><<<dim3(4, B/64), 256, 0, stream>>>(
      comb, fus_w, fus_b, fus_g, fus_be, fusedb, B, 256, 512, 256);
  const int NB = (Ncls + 127) / 128;       // 157 n-blocks
  mfma_cls_kernel<<<8*NB, 512, 0, stream>>>(fusedb, cls_w, cls_b, (float*)d_out,
                                            B, Ncls, 256);
}

// Round 6
// 650.370 us; speedup vs baseline: 1.0778x; 1.0778x over previous
//
#include <hip/hip_runtime.h>

#define NEG_SLOPE 0.2f
static constexpr float BN_INV = 0.9999950000374997f; // 1/sqrt(1+1e-5)

typedef __bf16 bf16x8 __attribute__((ext_vector_type(8)));
typedef float  f32x4  __attribute__((ext_vector_type(4)));

__device__ inline float4 bf4f(ushort4 u){
  float4 r;
  r.x = __uint_as_float((unsigned)u.x << 16);
  r.y = __uint_as_float((unsigned)u.y << 16);
  r.z = __uint_as_float((unsigned)u.z << 16);
  r.w = __uint_as_float((unsigned)u.w << 16);
  return r;
}
__device__ inline ushort4 f4bf(float4 v){
  ushort4 u;
  u.x = __builtin_bit_cast(unsigned short, (__bf16)v.x);
  u.y = __builtin_bit_cast(unsigned short, (__bf16)v.y);
  u.z = __builtin_bit_cast(unsigned short, (__bf16)v.z);
  u.w = __builtin_bit_cast(unsigned short, (__bf16)v.w);
  return u;
}

// ===================== CSR build =====================
__global__ void hist_kernel(const int* __restrict__ dst, int* __restrict__ cnt, int E){
  int e = blockIdx.x*256 + threadIdx.x;
  if (e < E) atomicAdd(&cnt[dst[e]], 1);
}

// multiblock scan: part 1 — per-1024-block local scan + block totals
__global__ __launch_bounds__(1024) void scan1_kernel(int* __restrict__ cnt_cursor,
                                                     int* __restrict__ offs,
                                                     int* __restrict__ bsum, int n){
  __shared__ int wsum[16];
  int tid = threadIdx.x, lane = tid & 63, wv = tid >> 6;
  int i = blockIdx.x*1024 + tid;
  int v = (i < n) ? cnt_cursor[i] : 0;
  int x = v;
#pragma unroll
  for (int off = 1; off < 64; off <<= 1){
    int t = __shfl_up(x, off);
    if (lane >= off) x += t;
  }
  if (lane == 63) wsum[wv] = x;
  __syncthreads();
  int y = (lane < 16) ? wsum[lane] : 0;
#pragma unroll
  for (int off = 1; off < 16; off <<= 1){
    int t = __shfl_up(y, off);
    if (lane >= off) y += t;
  }
  int excl  = (wv == 0) ? 0 : __shfl(y, wv - 1);
  int total = __shfl(y, 15);
  int inc = excl + x;                       // block-local inclusive
  if (i < n){ offs[i+1] = inc; cnt_cursor[i] = inc - v; }
  if (tid == 0) bsum[blockIdx.x] = total;
}

// part 2+3 merged — each block shuffle-reduces bsum[0..bid) itself (nb <= 64)
__global__ __launch_bounds__(1024) void scan3_kernel(int* __restrict__ offs, int* __restrict__ cursor,
                                                     const int* __restrict__ bsum, int n){
  __shared__ int base_s;
  if (threadIdx.x < 64){
    int lane = threadIdx.x;
    int v = (lane < (int)blockIdx.x) ? bsum[lane] : 0;
#pragma unroll
    for (int off = 1; off < 64; off <<= 1) v += __shfl_xor(v, off);
    if (lane == 0) base_s = v;
  }
  __syncthreads();
  int base = base_s;
  int i = blockIdx.x*1024 + threadIdx.x;
  if (i < n){ offs[i+1] += base; cursor[i] += base; }
  if (i == 0) offs[0] = 0;
}

// scatter: permute src + edge_attr into CSR(dst) order
__global__ void scatter_kernel(const int* __restrict__ src, const int* __restrict__ dst,
                               const float* __restrict__ ea, int* __restrict__ cursor,
                               int* __restrict__ perm_src, float* __restrict__ ea_perm, int E){
  int e = blockIdx.x*256 + threadIdx.x;
  if (e >= E) return;
  int d = dst[e];
  int pos = atomicAdd(&cursor[d], 1);
  perm_src[pos] = src[e];
#pragma unroll
  for (int k = 0; k < 6; ++k) ea_perm[(size_t)pos*6 + k] = ea[(size_t)e*6 + k];
}

// ===================== generic fp32 GEMM (MLP fuse layer), strided C =====================
template<bool USE_BIAS, bool USE_BN, bool USE_RELU, typename OutT>
__global__ __launch_bounds__(256) void gemm_kernel(
    const float* __restrict__ A, const float* __restrict__ W,
    const float* __restrict__ bias, const float* __restrict__ gam, const float* __restrict__ bet,
    OutT* __restrict__ C, int M, int N, int K, int LDC)
{
  __shared__ float As[32][68];
  __shared__ float Bs[32][64];
  int tid = threadIdx.x;
  int tx = tid & 15, ty = tid >> 4;
  int bn0 = blockIdx.x * 64, bm0 = blockIdx.y * 64;
  float acc[4][4] = {};
  for (int k0 = 0; k0 < K; k0 += 32){
    int kk = tid & 31, mm0 = tid >> 5;
#pragma unroll
    for (int r = 0; r < 8; ++r){
      int ml = mm0 + r*8;
      int m = bm0 + ml;
      As[kk][ml] = (m < M) ? A[(size_t)m*K + k0 + kk] : 0.f;
    }
    int nn = tid & 63, kb = tid >> 6;
#pragma unroll
    for (int r = 0; r < 8; ++r){
      int kl = kb + r*4;
      int n = bn0 + nn;
      Bs[kl][nn] = (n < N) ? W[(size_t)(k0 + kl)*N + n] : 0.f;
    }
    __syncthreads();
#pragma unroll
    for (int k = 0; k < 32; ++k){
      float4 a4 = *reinterpret_cast<const float4*>(&As[k][ty*4]);
      float4 b4 = *reinterpret_cast<const float4*>(&Bs[k][tx*4]);
      acc[0][0] += a4.x*b4.x; acc[0][1] += a4.x*b4.y; acc[0][2] += a4.x*b4.z; acc[0][3] += a4.x*b4.w;
      acc[1][0] += a4.y*b4.x; acc[1][1] += a4.y*b4.y; acc[1][2] += a4.y*b4.z; acc[1][3] += a4.y*b4.w;
      acc[2][0] += a4.z*b4.x; acc[2][1] += a4.z*b4.y; acc[2][2] += a4.z*b4.z; acc[2][3] += a4.z*b4.w;
      acc[3][0] += a4.w*b4.x; acc[3][1] += a4.w*b4.y; acc[3][2] += a4.w*b4.z; acc[3][3] += a4.w*b4.w;
    }
    __syncthreads();
  }
#pragma unroll
  for (int i = 0; i < 4; ++i){
    int m = bm0 + ty*4 + i;
    if (m < M){
#pragma unroll
      for (int j = 0; j < 4; ++j){
        int n = bn0 + tx*4 + j;
        if (n < N){
          float c = acc[i][j];
          if (USE_BIAS) c += bias[n];
          if (USE_BN)   c = gam[n]*c*BN_INV + bet[n];
          if (USE_RELU) c = fmaxf(c, 0.f);
          C[(size_t)m*LDC + n] = (OutT)c;
        }
      }
    }
  }
}

// ===================== fused MLP: netemb = relu(bn2(relu(bn1(nf@w1+b1))@w2+b2)) ==========
// h1 (the A-tile) is computed in staging from nf (LDS-cached 64x10) and w1 columns.
// N=K=256 fixed; writes f32 into C (comb+256) with LDC stride.
__global__ __launch_bounds__(256) void netemb_kernel(
    const float* __restrict__ nf, const float* __restrict__ w1, const float* __restrict__ b1,
    const float* __restrict__ g1, const float* __restrict__ be1,
    const float* __restrict__ w2, const float* __restrict__ b2,
    const float* __restrict__ g2, const float* __restrict__ be2,
    float* __restrict__ C, int M, int LDC)
{
  __shared__ float As[32][68];
  __shared__ float Bs[32][64];
  __shared__ float nfs[64][10];
  int tid = threadIdx.x;
  int tx = tid & 15, ty = tid >> 4;
  int bn0 = blockIdx.x * 64, bm0 = blockIdx.y * 64;
  for (int t = tid; t < 640; t += 256)
    nfs[t/10][t%10] = nf[(size_t)(bm0 + t/10)*10 + t%10];   // M % 64 == 0
  __syncthreads();
  float acc[4][4] = {};
  for (int k0 = 0; k0 < 256; k0 += 32){
    int kk = tid & 31, mm0 = tid >> 5;
    {
      int kcol = k0 + kk;
      float wc[10];
#pragma unroll
      for (int j = 0; j < 10; ++j) wc[j] = w1[j*256 + kcol];
      float scale1 = g1[kcol]*BN_INV;
      float off1   = g1[kcol]*b1[kcol]*BN_INV + be1[kcol];
#pragma unroll
      for (int r = 0; r < 8; ++r){
        int ml = mm0 + r*8;
        float s = 0.f;
#pragma unroll
        for (int j = 0; j < 10; ++j) s += nfs[ml][j]*wc[j];
        As[kk][ml] = fmaxf(s*scale1 + off1, 0.f);
      }
    }
    int nn = tid & 63, kb = tid >> 6;
#pragma unroll
    for (int r = 0; r < 8; ++r){
      int kl = kb + r*4;
      Bs[kl][nn] = w2[(size_t)(k0 + kl)*256 + bn0 + nn];
    }
    __syncthreads();
#pragma unroll
    for (int k = 0; k < 32; ++k){
      float4 a4 = *reinterpret_cast<const float4*>(&As[k][ty*4]);
      float4 b4 = *reinterpret_cast<const float4*>(&Bs[k][tx*4]);
      acc[0][0] += a4.x*b4.x; acc[0][1] += a4.x*b4.y; acc[0][2] += a4.x*b4.z; acc[0][3] += a4.x*b4.w;
      acc[1][0] += a4.y*b4.x; acc[1][1] += a4.y*b4.y; acc[1][2] += a4.y*b4.z; acc[1][3] += a4.y*b4.w;
      acc[2][0] += a4.z*b4.x; acc[2][1] += a4.z*b4.y; acc[2][2] += a4.z*b4.z; acc[2][3] += a4.z*b4.w;
      acc[3][0] += a4.w*b4.x; acc[3][1] += a4.w*b4.y; acc[3][2] += a4.w*b4.z; acc[3][3] += a4.w*b4.w;
    }
    __syncthreads();
  }
#pragma unroll
  for (int i = 0; i < 4; ++i){
    int m = bm0 + ty*4 + i;
#pragma unroll
    for (int j = 0; j < 4; ++j){
      int n = bn0 + tx*4 + j;
      float c = acc[i][j] + b2[n];
      c = g2[n]*c*BN_INV + be2[n];
      C[(size_t)m*LDC + n] = fmaxf(c, 0.f);
    }
  }
}

// ===================== transpose+convert W [K,N] f32 -> [N,K] bf16 =====================
__global__ void wtrans_kernel(const float* __restrict__ W, __bf16* __restrict__ Wt, int K, int N){
  __shared__ float tile[32][33];
  int n0 = blockIdx.x*32, k0 = blockIdx.y*32;
  int t = threadIdx.x;
  int nl = t & 31, kl = t >> 5;
#pragma unroll
  for (int r = 0; r < 4; ++r)
    tile[kl + r*8][nl] = W[(size_t)(k0 + kl + r*8)*N + n0 + nl];
  __syncthreads();
  int nl2 = t >> 3, kc = (t & 7)*4;
#pragma unroll
  for (int j = 0; j < 4; ++j)
    Wt[(size_t)(n0 + nl2)*K + k0 + kc + j] = (__bf16)tile[kc + j][nl2];
}

// wtrans for the 3 GAT weight matrices + folded We@ae (z==3 slice)
__global__ void wtrans3_kernel(const float* __restrict__ W0, const float* __restrict__ W1,
                               const float* __restrict__ W2, __bf16* __restrict__ Wt,
                               const float* __restrict__ We1, const float* __restrict__ ae1,
                               const float* __restrict__ We2, const float* __restrict__ ae2,
                               const float* __restrict__ We3, const float* __restrict__ ae3,
                               float* __restrict__ M){
  if (blockIdx.z == 3){
    if (blockIdx.x != 0 || blockIdx.y != 0) return;
    int t = threadIdx.x;   // 256, use first 102
    if (t < 96){
      const float* We = (t < 48) ? We1 : We2;
      const float* ae = (t < 48) ? ae1 : ae2;
      int u = t % 48, k = u / 8, h = u % 8;
      float s = 0.f;
      for (int c = 0; c < 32; ++c) s += We[k*256 + h*32 + c] * ae[h*32 + c];
      M[t] = s;
    } else if (t < 102){
      int k = t - 96;
      float s = 0.f;
      for (int c = 0; c < 256; ++c) s += We3[k*256 + c] * ae3[c];
      M[t] = s;
    }
    return;
  }
  __shared__ float tile[32][33];
  const float* W = (blockIdx.z == 0) ? W0 : (blockIdx.z == 1) ? W1 : W2;
  __bf16* D = Wt + (size_t)blockIdx.z * 65536;
  int n0 = blockIdx.x*32, k0 = blockIdx.y*32;
  int t = threadIdx.x;
  int nl = t & 31, kl = t >> 5;
#pragma unroll
  for (int r = 0; r < 4; ++r)
    tile[kl + r*8][nl] = W[(size_t)(k0 + kl + r*8)*256 + n0 + nl];
  __syncthreads();
  int nl2 = t >> 3, kc = (t & 7)*4;
#pragma unroll
  for (int j = 0; j < 4; ++j)
    D[(size_t)(n0 + nl2)*256 + k0 + kc + j] = (__bf16)tile[kc + j][nl2];
}

// ===================== bf16 MFMA GEMM: C[M,N] = A[M,K] * Bt[N,K]^T =====================
// BM=128, BN=128, BK=64; 256 thr = 4 waves (2x2), each wave 64x64 via 4x4 mfma_16x16x32
// AF32: A is f32, converted to bf16 during staging (bounds-checked).
// ALSD==8: fuse per-row attention dots als/ald (H=8) from f32 accumulators, direct store.
// ALSD==1: fuse per-row dots (H=1, full 256-col row) via atomicAdd into zeroed als/ald.
template<bool AF32, int ALSD, typename OutT>
__global__ __launch_bounds__(256) void mfma_gemm_kernel(
    const void* __restrict__ Aptr, const __bf16* __restrict__ Bt,
    OutT* __restrict__ C, int M, int N, int K,
    const float* __restrict__ a_s, const float* __restrict__ a_d,
    float* __restrict__ als, float* __restrict__ ald)
{
  const __bf16* Ab = (const __bf16*)Aptr;
  const float*  Af = (const float*) Aptr;
  __shared__ __bf16 As[128*72];
  __shared__ __bf16 Bs[128*72];
  int tid = threadIdx.x;
  int lane = tid & 63, w = tid >> 6;
  int quad = lane >> 4, l16 = lane & 15;
  int wm = (w & 1) * 64, wn = (w >> 1) * 64;
  int bn0 = blockIdx.x * 128, bm0 = blockIdx.y * 128;
  f32x4 acc[4][4] = {};
  for (int k0 = 0; k0 < K; k0 += 64){
#pragma unroll
    for (int p = 0; p < 4; ++p){
      int idx = p*256 + tid;
      int row = idx >> 3, ch = idx & 7;
      uint4 av;
      if constexpr (AF32){
        av = make_uint4(0,0,0,0);
        int m = bm0 + row;
        if (m < M){
          const float4* A4 = reinterpret_cast<const float4*>(&Af[(size_t)m*K + k0 + ch*8]);
          float4 x0 = A4[0], x1 = A4[1];
          ushort4 u0 = f4bf(x0), u1 = f4bf(x1);
          av = make_uint4((unsigned)u0.x | ((unsigned)u0.y << 16),
                          (unsigned)u0.z | ((unsigned)u0.w << 16),
                          (unsigned)u1.x | ((unsigned)u1.y << 16),
                          (unsigned)u1.z | ((unsigned)u1.w << 16));
        }
      } else {
        av = *reinterpret_cast<const uint4*>(&Ab[(size_t)(bm0 + row)*K + k0 + ch*8]);
      }
      *reinterpret_cast<uint4*>(&As[row*72 + ch*8]) = av;
      int n = bn0 + row;
      uint4 bv = make_uint4(0,0,0,0);
      if (n < N) bv = *reinterpret_cast<const uint4*>(&Bt[(size_t)n*K + k0 + ch*8]);
      *reinterpret_cast<uint4*>(&Bs[row*72 + ch*8]) = bv;
    }
    __syncthreads();
#pragma unroll
    for (int s = 0; s < 2; ++s){
      bf16x8 af[4], bfr[4];
#pragma unroll
      for (int t4 = 0; t4 < 4; ++t4){
        af[t4]  = *reinterpret_cast<const bf16x8*>(&As[(wm + t4*16 + l16)*72 + s*32 + quad*8]);
        bfr[t4] = *reinterpret_cast<const bf16x8*>(&Bs[(wn + t4*16 + l16)*72 + s*32 + quad*8]);
      }
#pragma unroll
      for (int mt = 0; mt < 4; ++mt)
#pragma unroll
        for (int nt = 0; nt < 4; ++nt)
          acc[mt][nt] = __builtin_amdgcn_mfma_f32_16x16x32_bf16(af[mt], bfr[nt], acc[mt][nt], 0, 0, 0);
    }
    __syncthreads();
  }
  // C/D layout: col = lane&15, row = quad*4 + reg  [m89-verified]
#pragma unroll
  for (int mt = 0; mt < 4; ++mt){
#pragma unroll
    for (int nt = 0; nt < 4; ++nt){
      int n = bn0 + wn + nt*16 + l16;
      if (n < N){
#pragma unroll
        for (int r = 0; r < 4; ++r){
          int m = bm0 + wm + mt*16 + quad*4 + r;
          if (m < M) C[(size_t)m*N + n] = (OutT)(acc[mt][nt][r]);
        }
      }
    }
  }
  if constexpr (ALSD != 0){
    float av4[4], dv4[4];
#pragma unroll
    for (int nt = 0; nt < 4; ++nt){
      int n = bn0 + wn + nt*16 + l16;   // N==256 for xp GEMMs, always in range
      av4[nt] = a_s[n];
      dv4[nt] = a_d[n];
    }
    int hb = (bn0 + wn) >> 5;           // first head in this wave's 64-col span (ALSD==8)
#pragma unroll
    for (int mt = 0; mt < 4; ++mt){
#pragma unroll
      for (int r = 0; r < 4; ++r){
        float s0 = acc[mt][0][r]*av4[0] + acc[mt][1][r]*av4[1];
        float s1 = acc[mt][2][r]*av4[2] + acc[mt][3][r]*av4[3];
        float d0 = acc[mt][0][r]*dv4[0] + acc[mt][1][r]*dv4[1];
        float d1 = acc[mt][2][r]*dv4[2] + acc[mt][3][r]*dv4[3];
#pragma unroll
        for (int off = 1; off < 16; off <<= 1){
          s0 += __shfl_xor(s0, off); s1 += __shfl_xor(s1, off);
          d0 += __shfl_xor(d0, off); d1 += __shfl_xor(d1, off);
        }
        if (l16 == 0){
          int m = bm0 + wm + mt*16 + quad*4 + r;
          if (m < M){
            if constexpr (ALSD == 8){
              als[m*8 + hb]     = s0; als[m*8 + hb + 1] = s1;
              ald[m*8 + hb]     = d0; ald[m*8 + hb + 1] = d1;
            } else {  // ALSD == 1: partial over this wave's 64 cols -> atomic
              atomicAdd(&als[m], s0 + s1);
              atomicAdd(&ald[m], d0 + d1);
            }
          }
        }
      }
    }
  }
}

// ===================== classify GEMM: BM=256, BN=128, 512 thr = 8 waves (4m x 2n) ========
// C f32 = A[M,K]bf16 * Bt[N,K]bf16^T + bias.  M must be a multiple of 256.
// XCD-chunk swizzle: all 8 m-blocks of one B-panel land on one XCD -> B read from L3 ~once.
__global__ __launch_bounds__(512) void mfma_cls_kernel(
    const __bf16* __restrict__ A, const __bf16* __restrict__ Bt,
    const float* __restrict__ bias, float* __restrict__ C, int M, int N, int K)
{
  __shared__ __bf16 As[256*72];
  __shared__ __bf16 Bs[128*72];
  int tid = threadIdx.x;
  int lane = tid & 63, w = tid >> 6;       // 8 waves
  int quad = lane >> 4, l16 = lane & 15;
  int wm = (w >> 1) * 64, wn = (w & 1) * 64;
  int nwg = gridDim.x;                     // 8 * NB, NB = n-blocks
  int chunk = nwg >> 3;
  int orig = (blockIdx.x & 7) * chunk + (blockIdx.x >> 3);
  int bm0 = (orig & 7) * 256, bn0 = (orig >> 3) * 128;
  f32x4 acc[4][4] = {};
  for (int k0 = 0; k0 < K; k0 += 64){
#pragma unroll
    for (int p = 0; p < 4; ++p){
      int idx = p*512 + tid;
      int row = idx >> 3, ch = idx & 7;    // row 0..255
      uint4 av = *reinterpret_cast<const uint4*>(&A[(size_t)(bm0 + row)*K + k0 + ch*8]);
      *reinterpret_cast<uint4*>(&As[row*72 + ch*8]) = av;
    }
#pragma unroll
    for (int p = 0; p < 2; ++p){
      int idx = p*512 + tid;
      int row = idx >> 3, ch = idx & 7;    // row 0..127
      int n = bn0 + row;
      uint4 bv = make_uint4(0,0,0,0);
      if (n < N) bv = *reinterpret_cast<const uint4*>(&Bt[(size_t)n*K + k0 + ch*8]);
      *reinterpret_cast<uint4*>(&Bs[row*72 + ch*8]) = bv;
    }
    __syncthreads();
#pragma unroll
    for (int s = 0; s < 2; ++s){
      bf16x8 af[4], bfr[4];
#pragma unroll
      for (int t4 = 0; t4 < 4; ++t4){
        af[t4]  = *reinterpret_cast<const bf16x8*>(&As[(wm + t4*16 + l16)*72 + s*32 + quad*8]);
        bfr[t4] = *reinterpret_cast<const bf16x8*>(&Bs[(wn + t4*16 + l16)*72 + s*32 + quad*8]);
      }
#pragma unroll
      for (int mt = 0; mt < 4; ++mt)
#pragma unroll
        for (int nt = 0; nt < 4; ++nt)
          acc[mt][nt] = __builtin_amdgcn_mfma_f32_16x16x32_bf16(af[mt], bfr[nt], acc[mt][nt], 0, 0, 0);
    }
    __syncthreads();
  }
#pragma unroll
  for (int mt = 0; mt < 4; ++mt){
#pragma unroll
    for (int nt = 0; nt < 4; ++nt){
      int n = bn0 + wn + nt*16 + l16;
      if (n < N){
        float bv = bias[n];
#pragma unroll
        for (int r = 0; r < 4; ++r){
          int m = bm0 + wm + mt*16 + quad*4 + r;   // M % 256 == 0: always in range
          C[(size_t)m*N + n] = acc[mt][nt][r] + bv;
        }
      }
    }
  }
}

// ===================== fused per-node attention + aggregation (single pass, H=8) ==========
// w_i = exp(alpha_i)/(sum exp + 1e-16); max-subtraction omitted (|alpha| small)
__global__ void agg8_kernel(const int* __restrict__ offs, const int* __restrict__ perm_src,
                            const float* __restrict__ ea_perm, const float* __restrict__ Mf,
                            const float* __restrict__ als, const float* __restrict__ ald,
                            const __bf16* __restrict__ xp, const float* __restrict__ bias,
                            __bf16* __restrict__ out, int Nn){
  int gid = blockIdx.x*blockDim.x + threadIdx.x;
  int wave = gid >> 6, lane = threadIdx.x & 63;
  if (wave >= Nn) return;
  int beg = offs[wave], end = offs[wave+1];
  int hsel = lane >> 3;

  float mk[6];
#pragma unroll
  for (int k = 0; k < 6; ++k) mk[k] = Mf[k*8 + hsel];
  float aldv = ald[(size_t)wave*8 + hsel];

  const ushort4* X4 = reinterpret_cast<const ushort4*>(xp);
  float4 acc = make_float4(0.f,0.f,0.f,0.f);
  float den = 0.f;

  int i = beg;
  for (; i + 3 < end; i += 4){
    int s0 = perm_src[i], s1 = perm_src[i+1], s2 = perm_src[i+2], s3 = perm_src[i+3];
    float a0 = als[(size_t)s0*8 + hsel] + aldv;
    float a1 = als[(size_t)s1*8 + hsel] + aldv;
    float a2 = als[(size_t)s2*8 + hsel] + aldv;
    float a3 = als[(size_t)s3*8 + hsel] + aldv;
#pragma unroll
    for (int k = 0; k < 6; ++k){
      a0 += ea_perm[(size_t)i*6 + k]     * mk[k];
      a1 += ea_perm[(size_t)(i+1)*6 + k] * mk[k];
      a2 += ea_perm[(size_t)(i+2)*6 + k] * mk[k];
      a3 += ea_perm[(size_t)(i+3)*6 + k] * mk[k];
    }
    a0 = (a0 > 0.f) ? a0 : NEG_SLOPE*a0;
    a1 = (a1 > 0.f) ? a1 : NEG_SLOPE*a1;
    a2 = (a2 > 0.f) ? a2 : NEG_SLOPE*a2;
    a3 = (a3 > 0.f) ? a3 : NEG_SLOPE*a3;
    float e0 = __expf(a0), e1 = __expf(a1), e2 = __expf(a2), e3 = __expf(a3);
    den += (e0 + e1) + (e2 + e3);
    float4 x0 = bf4f(X4[(size_t)s0*64 + lane]);
    float4 x1 = bf4f(X4[(size_t)s1*64 + lane]);
    float4 x2 = bf4f(X4[(size_t)s2*64 + lane]);
    float4 x3 = bf4f(X4[(size_t)s3*64 + lane]);
    acc.x += x0.x*e0 + x1.x*e1 + x2.x*e2 + x3.x*e3;
    acc.y += x0.y*e0 + x1.y*e1 + x2.y*e2 + x3.y*e3;
    acc.z += x0.z*e0 + x1.z*e1 + x2.z*e2 + x3.z*e3;
    acc.w += x0.w*e0 + x1.w*e1 + x2.w*e2 + x3.w*e3;
  }
  for (; i < end; ++i){
    int s = perm_src[i];
    float a = als[(size_t)s*8 + hsel] + aldv;
#pragma unroll
    for (int k = 0; k < 6; ++k) a += ea_perm[(size_t)i*6 + k] * mk[k];
    a = (a > 0.f) ? a : NEG_SLOPE*a;
    float e = __expf(a);
    den += e;
    float4 xv = bf4f(X4[(size_t)s*64 + lane]);
    acc.x += xv.x*e; acc.y += xv.y*e; acc.z += xv.z*e; acc.w += xv.w*e;
  }

  float r = 1.f / (den + 1e-16f);
  float4 bv = reinterpret_cast<const float4*>(bias)[lane];
  acc.x = fmaxf(acc.x*r + bv.x, 0.f); acc.y = fmaxf(acc.y*r + bv.y, 0.f);
  acc.z = fmaxf(acc.z*r + bv.z, 0.f); acc.w = fmaxf(acc.w*r + bv.w, 0.f);
  reinterpret_cast<ushort4*>(out)[(size_t)wave*64 + lane] = f4bf(acc);
}

// ===================== layer-3 aggregation, QUERIED NODES ONLY (H=1) ==========
// One wave per batch element b; node = ids[b]; writes f32 directly into comb[b][0:256].
__global__ void agg1q_kernel(const int* __restrict__ ids, const int* __restrict__ offs,
                             const int* __restrict__ perm_src, const float* __restrict__ ea_perm,
                             const float* __restrict__ Mf, const float* __restrict__ als,
                             const float* __restrict__ ald, const __bf16* __restrict__ xp,
                             const float* __restrict__ bias, float* __restrict__ comb, int B){
  int gid = blockIdx.x*blockDim.x + threadIdx.x;
  int wave = gid >> 6, lane = threadIdx.x & 63;
  if (wave >= B) return;
  int node = ids[wave];
  int beg = offs[node], end = offs[node+1];

  float mk[6];
#pragma unroll
  for (int k = 0; k < 6; ++k) mk[k] = Mf[k];
  float aldv = ald[node];

  const ushort4* X4 = reinterpret_cast<const ushort4*>(xp);
  float4 acc = make_float4(0.f,0.f,0.f,0.f);
  float den = 0.f;

  int i = beg;
  for (; i + 3 < end; i += 4){
    int s0 = perm_src[i], s1 = perm_src[i+1], s2 = perm_src[i+2], s3 = perm_src[i+3];
    float a0 = als[s0] + aldv, a1 = als[s1] + aldv;
    float a2 = als[s2] + aldv, a3 = als[s3] + aldv;
#pragma unroll
    for (int k = 0; k < 6; ++k){
      a0 += ea_perm[(size_t)i*6 + k]     * mk[k];
      a1 += ea_perm[(size_t)(i+1)*6 + k] * mk[k];
      a2 += ea_perm[(size_t)(i+2)*6 + k] * mk[k];
      a3 += ea_perm[(size_t)(i+3)*6 + k] * mk[k];
    }
    a0 = (a0 > 0.f) ? a0 : NEG_SLOPE*a0;
    a1 = (a1 > 0.f) ? a1 : NEG_SLOPE*a1;
    a2 = (a2 > 0.f) ? a2 : NEG_SLOPE*a2;
    a3 = (a3 > 0.f) ? a3 : NEG_SLOPE*a3;
    float e0 = __expf(a0), e1 = __expf(a1), e2 = __expf(a2), e3 = __expf(a3);
    den += (e0 + e1) + (e2 + e3);
    float4 x0 = bf4f(X4[(size_t)s0*64 + lane]);
    float4 x1 = bf4f(X4[(size_t)s1*64 + lane]);
    float4 x2 = bf4f(X4[(size_t)s2*64 + lane]);
    float4 x3 = bf4f(X4[(size_t)s3*64 + lane]);
    acc.x += x0.x*e0 + x1.x*e1 + x2.x*e2 + x3.x*e3;
    acc.y += x0.y*e0 + x1.y*e1 + x2.y*e2 + x3.y*e3;
    acc.z += x0.z*e0 + x1.z*e1 + x2.z*e2 + x3.z*e3;
    acc.w += x0.w*e0 + x1.w*e1 + x2.w*e2 + x3.w*e3;
  }
  for (; i < end; ++i){
    int s = perm_src[i];
    float a = als[s] + aldv;
#pragma unroll
    for (int k = 0; k < 6; ++k) a += ea_perm[(size_t)i*6 + k] * mk[k];
    a = (a > 0.f) ? a : NEG_SLOPE*a;
    float e = __expf(a);
    den += e;
    float4 xv = bf4f(X4[(size_t)s*64 + lane]);
    acc.x += xv.x*e; acc.y += xv.y*e; acc.z += xv.z*e; acc.w += xv.w*e;
  }

  float r = 1.f / (den + 1e-16f);
  float4 bv = reinterpret_cast<const float4*>(bias)[lane];
  acc.x = acc.x*r + bv.x; acc.y = acc.y*r + bv.y;
  acc.z = acc.z*r + bv.z; acc.w = acc.w*r + bv.w;
  reinterpret_cast<float4*>(comb)[(size_t)wave*128 + lane] = acc;  // cols [0,256)
}

// ===================== host =====================
extern "C" void kernel_launch(void* const* d_in, const int* in_sizes, int n_in,
                              void* d_out, int out_size, void* d_ws, size_t ws_size,
                              hipStream_t stream)
{
  const int*   ids   = (const int*)  d_in[0];
  const float* nf    = (const float*)d_in[1];
  const int*   eidx  = (const int*)  d_in[2];
  const float* eattr = (const float*)d_in[3];
  const float* emb   = (const float*)d_in[4];
  const float* w1    = (const float*)d_in[5];
  const float* b1    = (const float*)d_in[6];
  const float* g1    = (const float*)d_in[7];
  const float* be1   = (const float*)d_in[8];
  const float* w2    = (const float*)d_in[9];
  const float* b2    = (const float*)d_in[10];
  const float* g2    = (const float*)d_in[11];
  const float* be2   = (const float*)d_in[12];
  const float* gW[3]  = {(const float*)d_in[13], (const float*)d_in[19], (const float*)d_in[25]};
  const float* gas[3] = {(const float*)d_in[14], (const float*)d_in[20], (const float*)d_in[26]};
  const float* gad[3] = {(const float*)d_in[15], (const float*)d_in[21], (const float*)d_in[27]};
  const float* gWe[3] = {(const float*)d_in[16], (const float*)d_in[22], (const float*)d_in[28]};
  const float* gae[3] = {(const float*)d_in[17], (const float*)d_in[23], (const float*)d_in[29]};
  const float* gb[3]  = {(const float*)d_in[18], (const float*)d_in[24], (const float*)d_in[30]};
  const float* fus_w  = (const float*)d_in[31];
  const float* fus_b  = (const float*)d_in[32];
  const float* fus_g  = (const float*)d_in[33];
  const float* fus_be = (const float*)d_in[34];
  const float* cls_w  = (const float*)d_in[35];
  const float* cls_b  = (const float*)d_in[36];

  const int E  = in_sizes[3] / 6;     // 320000
  const int Nn = in_sizes[4] / 256;   // 20000
  const int B  = in_sizes[0];         // 2048
  const int Ncls = in_sizes[36];      // 20000
  const int Npad = (Nn + 127) & ~127; // 20096
  const int* src = eidx;
  const int* dst = eidx + E;

  char* wbase = (char*)d_ws;
  size_t woff = 0;
  auto carve = [&](size_t bytes)->void*{
    void* p = wbase + woff;
    woff = (woff + bytes + 255) & ~(size_t)255;
    return p;
  };
  int*    offs     = (int*)   carve((size_t)(Nn+1)*4);
  // zero-region: cursor, als3, ald3 carved contiguously, cleared by ONE memset
  int*    cursor   = (int*)   carve((size_t)Nn*4);
  float*  als3     = (float*) carve((size_t)Nn*4);
  float*  ald3     = (float*) carve((size_t)Nn*4);
  size_t  zero_bytes = (size_t)((char*)ald3 - (char*)cursor) + (size_t)Nn*4;
  int*    bsum     = (int*)   carve(64*4);
  int*    perm_src = (int*)   carve((size_t)E*4);
  float*  ea_perm  = (float*) carve((size_t)E*6*4);
  __bf16* xb0      = (__bf16*)carve((size_t)Npad*256*2);
  __bf16* xb1      = (__bf16*)carve((size_t)Npad*256*2);
  __bf16* xpb      = (__bf16*)carve((size_t)Npad*256*2);
  __bf16* gWt      = (__bf16*)carve((size_t)3*256*256*2);
  float*  als      = (float*) carve((size_t)Nn*8*4);
  float*  ald      = (float*) carve((size_t)Nn*8*4);
  float*  Mfold    = (float*) carve(128*4);
  float*  comb     = (float*) carve((size_t)B*512*4);
  __bf16* fusedb   = (__bf16*)carve((size_t)B*256*2);
  __bf16* clsWt    = (__bf16*)carve((size_t)Ncls*256*2);
  (void)ws_size; (void)n_in; (void)out_size;

  const int nb1024 = (Nn + 1023) / 1024;   // 20 scan blocks (<= 64)

  // ---- CSR build (dst fixed across layers) + zero als3/ald3 for layer-3 atomics ----
  hipMemsetAsync(cursor, 0, zero_bytes, stream);
  hist_kernel<<<(E+255)/256, 256, 0, stream>>>(dst, cursor, E);
  scan1_kernel<<<nb1024, 1024, 0, stream>>>(cursor, offs, bsum, Nn);
  scan3_kernel<<<nb1024, 1024, 0, stream>>>(offs, cursor, bsum, Nn);
  scatter_kernel<<<(E+255)/256, 256, 0, stream>>>(src, dst, eattr, cursor,
                                                  perm_src, ea_perm, E);

  // ---- weight prep (wtrans3 z=3 slice computes Mfold) ----
  wtrans3_kernel<<<dim3(8, 8, 4), 256, 0, stream>>>(gW[0], gW[1], gW[2], gWt,
                                                    gWe[0], gae[0], gWe[1], gae[1],
                                                    gWe[2], gae[2], Mfold);
  wtrans_kernel<<<dim3(Ncls/32, 256/32), 256, 0, stream>>>(cls_w, clsWt, 256, Ncls);

  // ---- GAT layers ----
  dim3 mfma_grid_xp(2, Npad/128);
  int node_blocks = (Nn*64 + 255)/256;

  // layer 1: A = emb (f32, converted in staging), fused alsd (H=8)
  mfma_gemm_kernel<true, 8, __bf16><<<mfma_grid_xp, 256, 0, stream>>>(
      emb, gWt, xpb, Nn, 256, 256, gas[0], gad[0], als, ald);
  agg8_kernel<<<node_blocks, 256, 0, stream>>>(offs, perm_src, ea_perm, Mfold,
                                               als, ald, xpb, gb[0], xb1, Nn);
  // layer 2
  mfma_gemm_kernel<false, 8, __bf16><<<mfma_grid_xp, 256, 0, stream>>>(
      xb1, gWt + 65536, xpb, Nn, 256, 256, gas[1], gad[1], als, ald);
  agg8_kernel<<<node_blocks, 256, 0, stream>>>(offs, perm_src, ea_perm, Mfold + 48,
                                               als, ald, xpb, gb[1], xb0, Nn);
  // layer 3 (H=1): alsd fused via atomics into zeroed als3/ald3; aggregate ONLY
  // the queried nodes, writing f32 straight into comb[:, 0:256]
  mfma_gemm_kernel<false, 1, __bf16><<<mfma_grid_xp, 256, 0, stream>>>(
      xb0, gWt + 131072, xpb, Nn, 256, 256, gas[2], gad[2], als3, ald3);
  agg1q_kernel<<<(B*64 + 255)/256, 256, 0, stream>>>(ids, offs, perm_src, ea_perm,
                                                     Mfold + 96, als3, ald3, xpb, gb[2], comb, B);

  // ---- MLP path fused into ONE kernel: netemb -> comb[:, 256:512] ----
  netemb_kernel<<<dim3(4, B/64), 256, 0, stream>>>(
      nf, w1, b1, g1, be1, w2, b2, g2, be2, comb + 256, B, 512);

  // ---- fuse (bf16 out) + classify (BM=256 MFMA, XCD-swizzled, bf16 Bt) ----
  gemm_kernel<true,true,true,__bf16><<<dim3(4, B/64), 256, 0, stream>>>(
      comb, fus_w, fus_b, fus_g, fus_be, fusedb, B, 256, 512, 256);
  const int NB = (Ncls + 127) / 128;       // 157 n-blocks
  mfma_cls_kernel<<<8*NB, 512, 0, stream>>>(fusedb, clsWt, cls_b, (float*)d_out,
                                            B, Ncls, 256);
}